// Round 3
// baseline (598.613 us; speedup 1.0000x reference)
//
#include <hip/hip_runtime.h>
#include <hip/hip_bf16.h>

#define N_ROWS 131072
#define DIM 64
#define K_CODES 1024

typedef float v2f __attribute__((ext_vector_type(2)));

// ws layout (floats): [0 .. K_CODES-1] = esq[k], [K_CODES] = loss accumulator

// esq[k] = np.sum(e*e, axis=1) with numpy's pairwise 8-accumulator order.
__global__ void vq_prep(const float* __restrict__ emb, float* __restrict__ ws) {
#pragma clang fp contract(off)
    int k = blockIdx.x * blockDim.x + threadIdx.x;
    if (k < K_CODES) {
        const float* e = emb + (size_t)k * DIM;
        float ee[DIM];
        #pragma unroll
        for (int d = 0; d < DIM; ++d) ee[d] = e[d] * e[d];  // elementwise pass, one rounding each
        float r[8];
        #pragma unroll
        for (int j = 0; j < 8; ++j) r[j] = ee[j];
        #pragma unroll
        for (int i = 8; i < DIM; i += 8)
            #pragma unroll
            for (int j = 0; j < 8; ++j) r[j] = r[j] + ee[i + j];
        ws[k] = ((r[0] + r[1]) + (r[2] + r[3])) + ((r[4] + r[5]) + (r[6] + r[7]));
    }
    if (blockIdx.x == 0 && threadIdx.x == 0) ws[K_CODES] = 0.f;
}

__global__ __launch_bounds__(256) void vq_main(const float* __restrict__ x,
                                               const float* __restrict__ emb,
                                               const float* __restrict__ ws,
                                               float* __restrict__ out,
                                               float* __restrict__ loss_acc) {
#pragma clang fp contract(off)
    const int row = blockIdx.x * 256 + threadIdx.x;

    // x row into registers
    float xv[DIM];
    const float4* xp = reinterpret_cast<const float4*>(x + (size_t)row * DIM);
    #pragma unroll
    for (int i = 0; i < DIM / 4; ++i) {
        float4 v = xp[i];
        xv[4 * i + 0] = v.x;
        xv[4 * i + 1] = v.y;
        xv[4 * i + 2] = v.z;
        xv[4 * i + 3] = v.w;
    }

    // xsq = np.sum(x*x, axis=1): elementwise square, then pairwise 8-accumulator
    float xsq;
    {
        float xx[DIM];
        #pragma unroll
        for (int d = 0; d < DIM; ++d) xx[d] = xv[d] * xv[d];
        float r[8];
        #pragma unroll
        for (int j = 0; j < 8; ++j) r[j] = xx[j];
        #pragma unroll
        for (int i = 8; i < DIM; i += 8)
            #pragma unroll
            for (int j = 0; j < 8; ++j) r[j] = r[j] + xx[i + j];
        xsq = ((r[0] + r[1]) + (r[2] + r[3])) + ((r[4] + r[5]) + (r[6] + r[7]));
    }

    float best = INFINITY;
    int bidx = 0;

    // dot = np.einsum (npyv contig_contig_outstride0_two emulation):
    //   4-lane accumulator (lane j <- d ≡ j mod 4), 16 elems per iter with the
    //   muladd chain a3b3 first: vaccum = a0b0+(a1b1+(a2b2+(a3b3+vaccum)));
    //   separate mul/add roundings (no FMA, baseline SSE); reduce (v0+v1)+(v2+v3).
    #pragma unroll 2
    for (int k = 0; k < K_CODES; ++k) {
        const float* ek = emb + (size_t)k * DIM;
        v2f accA = {0.f, 0.f};  // lanes 0,1
        v2f accB = {0.f, 0.f};  // lanes 2,3
        #pragma unroll
        for (int c = 0; c < DIM; c += 16) {
            #pragma unroll
            for (int b = 12; b >= 0; b -= 4) {   // block3, block2, block1, block0
                const int d = c + b;
                v2f pa, pb;
                pa.x = xv[d + 0] * ek[d + 0];
                pa.y = xv[d + 1] * ek[d + 1];
                pb.x = xv[d + 2] * ek[d + 2];
                pb.y = xv[d + 3] * ek[d + 3];
                accA = accA + pa;
                accB = accB + pb;
            }
        }
        float dot = (accA.x + accA.y) + (accB.x + accB.y);
        float t = xsq + ws[k];          // fl(xsq + esq)
        float dist = t - 2.0f * dot;    // fl(t - fl(2*dot)); 2*dot exact
        if (dist < best) { best = dist; bidx = k; }  // strict < == first-min
    }

    // Epilogue: gather winning code, straight-through output, loss partial.
    const float* q = emb + (size_t)bidx * DIM;
    float lsum = 0.f;
    float* orow = out + (size_t)row * DIM;
    #pragma unroll
    for (int d = 0; d < DIM; d += 4) {
        float4 o;
        float df0 = q[d + 0] - xv[d + 0], df1 = q[d + 1] - xv[d + 1];
        float df2 = q[d + 2] - xv[d + 2], df3 = q[d + 3] - xv[d + 3];
        lsum = fmaf(df0, df0, lsum);
        lsum = fmaf(df1, df1, lsum);
        lsum = fmaf(df2, df2, lsum);
        lsum = fmaf(df3, df3, lsum);
        o.x = xv[d + 0] + df0;   // x + (q - x), reference op order
        o.y = xv[d + 1] + df1;
        o.z = xv[d + 2] + df2;
        o.w = xv[d + 3] + df3;
        *reinterpret_cast<float4*>(orow + d) = o;
    }

    out[(size_t)N_ROWS * DIM + row] = (float)bidx;

    #pragma unroll
    for (int off = 32; off > 0; off >>= 1) lsum += __shfl_down(lsum, off, 64);
    if ((threadIdx.x & 63) == 0) atomicAdd(loss_acc, lsum);
}

__global__ void vq_final(const float* __restrict__ loss_acc, float* __restrict__ out_loss) {
    if (threadIdx.x == 0 && blockIdx.x == 0) {
        float mean = loss_acc[0] / (float)((size_t)N_ROWS * DIM);
        out_loss[0] = mean;
    }
}

extern "C" void kernel_launch(void* const* d_in, const int* in_sizes, int n_in,
                              void* d_out, int out_size, void* d_ws, size_t ws_size,
                              hipStream_t stream) {
    const float* x   = (const float*)d_in[0];
    const float* emb = (const float*)d_in[1];
    float* out = (float*)d_out;
    float* ws = (float*)d_ws;

    vq_prep<<<dim3((K_CODES + 255) / 256), dim3(256), 0, stream>>>(emb, ws);
    vq_main<<<dim3(N_ROWS / 256), dim3(256), 0, stream>>>(x, emb, ws, out, ws + K_CODES);
    vq_final<<<dim3(1), dim3(1), 0, stream>>>(ws + K_CODES,
                                              out + (size_t)N_ROWS * DIM + N_ROWS);
}

// Round 4
// 340.781 us; speedup vs baseline: 1.7566x; 1.7566x over previous
//
#include <hip/hip_runtime.h>
#include <hip/hip_bf16.h>

#define N_ROWS 131072
#define DIM 64
#define K_CODES 1024
#define KSPLIT 4
#define KSEG (K_CODES / KSPLIT)   // 256
#define RPB 64                    // rows per block

typedef float v2f __attribute__((ext_vector_type(2)));

// ws layout (floats): [0 .. K_CODES-1] = esq[k], [K_CODES] = loss accumulator

// esq[k] = np.sum(e*e, axis=1) with numpy's pairwise 8-accumulator order.
__global__ void vq_prep(const float* __restrict__ emb, float* __restrict__ ws) {
#pragma clang fp contract(off)
    int k = blockIdx.x * blockDim.x + threadIdx.x;
    if (k < K_CODES) {
        const float* e = emb + (size_t)k * DIM;
        float ee[DIM];
        #pragma unroll
        for (int d = 0; d < DIM; ++d) ee[d] = e[d] * e[d];
        float r[8];
        #pragma unroll
        for (int j = 0; j < 8; ++j) r[j] = ee[j];
        #pragma unroll
        for (int i = 8; i < DIM; i += 8)
            #pragma unroll
            for (int j = 0; j < 8; ++j) r[j] = r[j] + ee[i + j];
        ws[k] = ((r[0] + r[1]) + (r[2] + r[3])) + ((r[4] + r[5]) + (r[6] + r[7]));
    }
    if (blockIdx.x == 0 && threadIdx.x == 0) ws[K_CODES] = 0.f;
}

__global__ __launch_bounds__(256, 4) void vq_main(const float* __restrict__ x,
                                                  const float* __restrict__ emb,
                                                  const float* __restrict__ ws,
                                                  float* __restrict__ out,
                                                  float* __restrict__ loss_acc) {
#pragma clang fp contract(off)
    const int lane = threadIdx.x & 63;
    // wave-uniform segment id (readfirstlane so the k-base is provably uniform
    // -> embedding reads stay s_load)
    const int w = __builtin_amdgcn_readfirstlane((int)(threadIdx.x >> 6));
    const int row = blockIdx.x * RPB + lane;
    const int kbase = w * KSEG;

    // x row in registers as 32 register-PAIRS (so v_pk ops need no v_mov pairing)
    v2f xv2[DIM / 2];
    const float4* xp = reinterpret_cast<const float4*>(x + (size_t)row * DIM);
    #pragma unroll
    for (int i = 0; i < DIM / 4; ++i) {
        float4 v = xp[i];
        xv2[2 * i + 0] = v2f{v.x, v.y};
        xv2[2 * i + 1] = v2f{v.z, v.w};
    }

    // xsq = np.sum(x*x): elementwise square then pairwise 8-accumulator (as R3)
    float xsq;
    {
        float xx[DIM];
        #pragma unroll
        for (int i = 0; i < DIM / 2; ++i) {
            xx[2 * i + 0] = xv2[i].x * xv2[i].x;
            xx[2 * i + 1] = xv2[i].y * xv2[i].y;
        }
        float r[8];
        #pragma unroll
        for (int j = 0; j < 8; ++j) r[j] = xx[j];
        #pragma unroll
        for (int i = 8; i < DIM; i += 8)
            #pragma unroll
            for (int j = 0; j < 8; ++j) r[j] = r[j] + xx[i + j];
        xsq = ((r[0] + r[1]) + (r[2] + r[3])) + ((r[4] + r[5]) + (r[6] + r[7]));
    }

    float best = INFINITY;
    int bidx = 0;

    // numpy einsum emulation (same chain as R3, which matched bit-exactly),
    // but with packed f32 ops: lanes {0,1}->accA, {2,3}->accB; 16-elem chunks,
    // blocks added in order 12,8,4,0; separate mul/add roundings (v_pk_mul +
    // v_pk_add are per-lane IEEE identical to v_mul/v_add).
    #pragma unroll 2
    for (int kk = 0; kk < KSEG; ++kk) {
        const int k = kbase + kk;
        const float* ek = emb + (size_t)k * DIM;   // wave-uniform -> s_load
        v2f accA = v2f{0.f, 0.f};
        v2f accB = v2f{0.f, 0.f};
        #pragma unroll
        for (int c = 0; c < DIM; c += 16) {
            #pragma unroll
            for (int b = 12; b >= 0; b -= 4) {
                const int d = c + b;
                v2f ea = *reinterpret_cast<const v2f*>(ek + d);
                v2f eb = *reinterpret_cast<const v2f*>(ek + d + 2);
                v2f pa, pb;
                asm("v_pk_mul_f32 %0, %1, %2" : "=v"(pa) : "s"(ea), "v"(xv2[(d >> 1) + 0]));
                asm("v_pk_mul_f32 %0, %1, %2" : "=v"(pb) : "s"(eb), "v"(xv2[(d >> 1) + 1]));
                asm("v_pk_add_f32 %0, %1, %0" : "+v"(accA) : "v"(pa));
                asm("v_pk_add_f32 %0, %1, %0" : "+v"(accB) : "v"(pb));
            }
        }
        float dot = (accA.x + accA.y) + (accB.x + accB.y);
        float t = xsq + ws[k];          // fl(xsq + esq)
        float dist = t - 2.0f * dot;    // fl(t - fl(2*dot)); 2*dot exact
        if (dist < best) { best = dist; bidx = k; }  // strict < == first-min
    }

    // combine the 4 segments per row via LDS, in segment order (lowest k wins ties)
    __shared__ float sdist[KSPLIT][RPB];
    __shared__ int   sidx[KSPLIT][RPB];
    sdist[w][lane] = best;
    sidx[w][lane]  = bidx;
    __syncthreads();

    if (w == 0) {
        float bestAll = sdist[0][lane];
        int   idxAll  = sidx[0][lane];
        #pragma unroll
        for (int s = 1; s < KSPLIT; ++s) {
            float ds_ = sdist[s][lane];
            int   is_ = sidx[s][lane];
            if (ds_ < bestAll) { bestAll = ds_; idxAll = is_; }
        }

        // epilogue (wave 0 owns all 64 rows; full xv2 in regs, static indexing)
        const float* q = emb + (size_t)idxAll * DIM;
        float* orow = out + (size_t)row * DIM;
        float lsum = 0.f;
        #pragma unroll
        for (int i = 0; i < DIM / 2; ++i) {
            const int d = 2 * i;
            float q0 = q[d + 0], q1 = q[d + 1];
            float df0 = q0 - xv2[i].x;
            float df1 = q1 - xv2[i].y;
            lsum = fmaf(df0, df0, lsum);
            lsum = fmaf(df1, df1, lsum);
            v2f o;
            o.x = xv2[i].x + df0;   // x + (q - x), reference op order
            o.y = xv2[i].y + df1;
            *reinterpret_cast<v2f*>(orow + d) = o;
        }

        out[(size_t)N_ROWS * DIM + row] = (float)idxAll;

        #pragma unroll
        for (int off = 32; off > 0; off >>= 1) lsum += __shfl_down(lsum, off, 64);
        if (lane == 0) atomicAdd(loss_acc, lsum);
    }
}

__global__ void vq_final(const float* __restrict__ loss_acc, float* __restrict__ out_loss) {
    if (threadIdx.x == 0 && blockIdx.x == 0) {
        float mean = loss_acc[0] / (float)((size_t)N_ROWS * DIM);
        out_loss[0] = mean;
    }
}

extern "C" void kernel_launch(void* const* d_in, const int* in_sizes, int n_in,
                              void* d_out, int out_size, void* d_ws, size_t ws_size,
                              hipStream_t stream) {
    const float* x   = (const float*)d_in[0];
    const float* emb = (const float*)d_in[1];
    float* out = (float*)d_out;
    float* ws = (float*)d_ws;

    vq_prep<<<dim3((K_CODES + 255) / 256), dim3(256), 0, stream>>>(emb, ws);
    vq_main<<<dim3(N_ROWS / RPB), dim3(256), 0, stream>>>(x, emb, ws, out, ws + K_CODES);
    vq_final<<<dim3(1), dim3(1), 0, stream>>>(ws + K_CODES,
                                              out + (size_t)N_ROWS * DIM + N_ROWS);
}